// Round 5
// baseline (519.263 us; speedup 1.0000x reference)
//
#include <hip/hip_runtime.h>

// B=16384, N=54, D_IN=64, D_HID=4, D_OUT=256
// Barrier-free fused kernel + Wf pre-transpose.
//
// Kernel A: transpose Wf[256][216] -> WfT[54][256] float4 (WfT[n*256+col] =
//           Wf[col][4n..4n+3]) in d_ws. 221 KB, one-off, L2-resident after.
// Kernel B: block 256 = 4 waves; wave owns 4 batch rows (16-lane group each).
//           Loop s=0..26 processes columns 2s,2s+1 with ONE set of weight LDS
//           reads (28 ds_read_b128 per 2 positions). Per column: 16-lane
//           xor-butterfly -> h; cross-group broadcast via v_readlane (SGPR,
//           no DS); FC reads WfT coalesced (4x float4/column, 1KB/inst, L2).
//           Zero barriers in the main loop -> loads pipeline freely.

#define N_POS   54
#define D_OUT   256
#define THREADS 256
#define RB      16

__global__ void transpose_wf_kernel(const float* __restrict__ Wf,
                                    float4* __restrict__ WfT)
{
    const int col = threadIdx.x;       // 0..255
    const int n   = blockIdx.x;        // 0..53
    const float4* Wf4 = (const float4*)Wf;     // [256][54]
    WfT[n * 256 + col] = Wf4[col * 54 + n];
}

#define DOT(D, W) ((D).x*(W).x + (D).y*(W).y + (D).z*(W).z + (D).w*(W).w)
#define RL(V, L)  __uint_as_float(__builtin_amdgcn_readlane(__float_as_uint(V), (L)))

template<bool USE_WT>
__global__ __launch_bounds__(THREADS)
void hexconv_fc_kernel(const float* __restrict__ x,
                       const float* __restrict__ nb,
                       const float* __restrict__ Wc,
                       const float* __restrict__ bc,
                       const float* __restrict__ Wd,
                       const float* __restrict__ bd,
                       const float* __restrict__ Wf,
                       const float* __restrict__ bf,
                       const float4* __restrict__ WfT,
                       float* __restrict__ out)
{
    // combined weights: wlds4[hh*112 + t + 16*j]; j=0 -> Wc, j>=1 -> Wd[j-1]
    __shared__ float4 wlds4[4 * 112];   // 7168 B

    const int tid  = threadIdx.x;
    const int wv   = tid >> 6;          // wave 0..3
    const int lane = tid & 63;
    const int g    = lane >> 4;         // group (row) 0..3
    const int t    = lane & 15;         // lane in group

    const float4* Wc4 = (const float4*)Wc;   // [4][16]
    const float4* Wd4 = (const float4*)Wd;   // [6][4][16]
    for (int idx = tid; idx < 4 * 112; idx += THREADS) {
        const int hh = idx / 112;
        const int f  = idx - hh * 112;
        float4 v;
        if (f < 16) {
            v = Wc4[hh * 16 + f];
        } else {
            const int k  = (f - 16) >> 4;
            const int d4 = (f - 16) & 15;
            v = Wd4[(k * 4 + hh) * 16 + d4];
        }
        wlds4[idx] = v;
    }

    // bias (lane-uniform -> scalar regs)
    float bias0 = bc[0], bias1 = bc[1], bias2 = bc[2], bias3 = bc[3];
#pragma unroll
    for (int k = 0; k < 6; ++k) {
        bias0 += bd[k * 4 + 0];
        bias1 += bd[k * 4 + 1];
        bias2 += bd[k * 4 + 2];
        bias3 += bd[k * 4 + 3];
    }

    const int b0 = blockIdx.x * RB;
    const size_t posBase = (size_t)(b0 + wv * 4 + g) * N_POS;

    const float4* x4  = (const float4*)x;    // [pos][16]
    const float4* nb4 = (const float4*)nb;   // [pos][96]
    const float4* Wf4 = (const float4*)Wf;   // [256][54]

    // FC accumulators: A{row g2}{col chunk j}
    float A00=0.f,A01=0.f,A02=0.f,A03=0.f;
    float A10=0.f,A11=0.f,A12=0.f,A13=0.f;
    float A20=0.f,A21=0.f,A22=0.f,A23=0.f;
    float A30=0.f,A31=0.f,A32=0.f,A33=0.f;

    __syncthreads();                         // the only barrier

    for (int s = 0; s < N_POS / 2; ++s) {
        const int n0 = 2 * s;
        const size_t p0 = posBase + n0;
        const float4* xp  = x4  + p0 * 16 + t;
        const float4* nbp = nb4 + p0 * 96 + t;

        // position n0 (even) and n0+1 (odd): 14 streaming loads
        const float4 e0 = xp[0];
        const float4 e1 = nbp[0],  e2 = nbp[16],  e3 = nbp[32];
        const float4 e4 = nbp[48], e5 = nbp[64],  e6 = nbp[80];
        const float4 f0 = xp[16];
        const float4 f1 = nbp[96],  f2 = nbp[112], f3 = nbp[128];
        const float4 f4 = nbp[144], f5 = nbp[160], f6 = nbp[176];

        // Wf for both columns (issued early; L2-resident)
        float4 we0, we1, we2, we3, wo0, wo1, wo2, wo3;
        if (USE_WT) {
            const float4* wte = WfT + n0 * 256 + lane;
            we0 = wte[0];   we1 = wte[64];  we2 = wte[128]; we3 = wte[192];
            wo0 = wte[256]; wo1 = wte[320]; wo2 = wte[384]; wo3 = wte[448];
        } else {
            we0 = Wf4[(size_t)(      lane) * 54 + n0];
            we1 = Wf4[(size_t)( 64 + lane) * 54 + n0];
            we2 = Wf4[(size_t)(128 + lane) * 54 + n0];
            we3 = Wf4[(size_t)(192 + lane) * 54 + n0];
            wo0 = Wf4[(size_t)(      lane) * 54 + n0 + 1];
            wo1 = Wf4[(size_t)( 64 + lane) * 54 + n0 + 1];
            wo2 = Wf4[(size_t)(128 + lane) * 54 + n0 + 1];
            wo3 = Wf4[(size_t)(192 + lane) * 54 + n0 + 1];
        }

        // hexconv dots, one weight read serves both positions
        float a0=0.f,a1=0.f,a2=0.f,a3=0.f;       // even col
        float c0=0.f,c1=0.f,c2=0.f,c3=0.f;       // odd col
#define HEX2(E, F, J) do {                                                     \
        float4 w_;                                                             \
        w_ = wlds4[0*112 + t + 16*(J)]; a0 += DOT(E, w_); c0 += DOT(F, w_);    \
        w_ = wlds4[1*112 + t + 16*(J)]; a1 += DOT(E, w_); c1 += DOT(F, w_);    \
        w_ = wlds4[2*112 + t + 16*(J)]; a2 += DOT(E, w_); c2 += DOT(F, w_);    \
        w_ = wlds4[3*112 + t + 16*(J)]; a3 += DOT(E, w_); c3 += DOT(F, w_);    \
    } while (0)
        HEX2(e0, f0, 0); HEX2(e1, f1, 1); HEX2(e2, f2, 2); HEX2(e3, f3, 3);
        HEX2(e4, f4, 4); HEX2(e5, f5, 5); HEX2(e6, f6, 6);
#undef HEX2

        // 16-lane xor-butterfly (both columns)
#pragma unroll
        for (int m = 1; m <= 8; m <<= 1) {
            a0 += __shfl_xor(a0, m, 64);  a1 += __shfl_xor(a1, m, 64);
            a2 += __shfl_xor(a2, m, 64);  a3 += __shfl_xor(a3, m, 64);
            c0 += __shfl_xor(c0, m, 64);  c1 += __shfl_xor(c1, m, 64);
            c2 += __shfl_xor(c2, m, 64);  c3 += __shfl_xor(c3, m, 64);
        }

        const float he0 = fmaxf(a0 + bias0, 0.f);
        const float he1 = fmaxf(a1 + bias1, 0.f);
        const float he2 = fmaxf(a2 + bias2, 0.f);
        const float he3 = fmaxf(a3 + bias3, 0.f);
        const float hf0 = fmaxf(c0 + bias0, 0.f);
        const float hf1 = fmaxf(c1 + bias1, 0.f);
        const float hf2 = fmaxf(c2 + bias2, 0.f);
        const float hf3 = fmaxf(c3 + bias3, 0.f);

        // FC: broadcast group g2's h via readlane (SGPR operand), accumulate
#define FC2(G2, AW, AX, AY, AZ) do {                                           \
        float h0_ = RL(he0, 16*(G2)), h1_ = RL(he1, 16*(G2));                  \
        float h2_ = RL(he2, 16*(G2)), h3_ = RL(he3, 16*(G2));                  \
        AW += h0_*we0.x + h1_*we0.y + h2_*we0.z + h3_*we0.w;                   \
        AX += h0_*we1.x + h1_*we1.y + h2_*we1.z + h3_*we1.w;                   \
        AY += h0_*we2.x + h1_*we2.y + h2_*we2.z + h3_*we2.w;                   \
        AZ += h0_*we3.x + h1_*we3.y + h2_*we3.z + h3_*we3.w;                   \
        h0_ = RL(hf0, 16*(G2)); h1_ = RL(hf1, 16*(G2));                        \
        h2_ = RL(hf2, 16*(G2)); h3_ = RL(hf3, 16*(G2));                        \
        AW += h0_*wo0.x + h1_*wo0.y + h2_*wo0.z + h3_*wo0.w;                   \
        AX += h0_*wo1.x + h1_*wo1.y + h2_*wo1.z + h3_*wo1.w;                   \
        AY += h0_*wo2.x + h1_*wo2.y + h2_*wo2.z + h3_*wo2.w;                   \
        AZ += h0_*wo3.x + h1_*wo3.y + h2_*wo3.z + h3_*wo3.w;                   \
    } while (0)
        FC2(0, A00, A01, A02, A03);
        FC2(1, A10, A11, A12, A13);
        FC2(2, A20, A21, A22, A23);
        FC2(3, A30, A31, A32, A33);
#undef FC2
    }

    // store: lane covers 4 rows x 4 cols, coalesced over lane
    const float bf0 = bf[lane];
    const float bf1 = bf[64 + lane];
    const float bf2 = bf[128 + lane];
    const float bf3 = bf[192 + lane];

#define ST(G2, AW, AX, AY, AZ) do {                                            \
        float* o_ = out + (size_t)(b0 + wv * 4 + (G2)) * D_OUT + lane;         \
        o_[0]   = AW + bf0;                                                    \
        o_[64]  = AX + bf1;                                                    \
        o_[128] = AY + bf2;                                                    \
        o_[192] = AZ + bf3;                                                    \
    } while (0)
    ST(0, A00, A01, A02, A03);
    ST(1, A10, A11, A12, A13);
    ST(2, A20, A21, A22, A23);
    ST(3, A30, A31, A32, A33);
#undef ST
}

extern "C" void kernel_launch(void* const* d_in, const int* in_sizes, int n_in,
                              void* d_out, int out_size, void* d_ws, size_t ws_size,
                              hipStream_t stream) {
    const float* x  = (const float*)d_in[0];
    const float* nb = (const float*)d_in[1];
    const float* Wc = (const float*)d_in[2];
    const float* bc = (const float*)d_in[3];
    const float* Wd = (const float*)d_in[4];
    const float* bd = (const float*)d_in[5];
    const float* Wf = (const float*)d_in[6];
    const float* bf = (const float*)d_in[7];
    float* out = (float*)d_out;

    const int B = 16384;
    const size_t wt_bytes = (size_t)N_POS * 256 * sizeof(float4);   // 221184

    dim3 grid(B / RB), block(THREADS);
    if (ws_size >= wt_bytes) {
        float4* WfT = (float4*)d_ws;
        transpose_wf_kernel<<<dim3(N_POS), dim3(256), 0, stream>>>(Wf, WfT);
        hexconv_fc_kernel<true><<<grid, block, 0, stream>>>(
            x, nb, Wc, bc, Wd, bd, Wf, bf, WfT, out);
    } else {
        hexconv_fc_kernel<false><<<grid, block, 0, stream>>>(
            x, nb, Wc, bc, Wd, bd, Wf, bf, nullptr, out);
    }
}